// Round 2
// 574.933 us; speedup vs baseline: 1.0330x; 1.0330x over previous
//
#include <hip/hip_runtime.h>
#include <cstdint>

#define N_TOK 8192
#define DIM   1024
#define DFF   4096
#define NEXP  8
#define CAP   1280
#define NSLOT (N_TOK * 2)
#define SCAN_WAVES 16

typedef __attribute__((ext_vector_type(8))) __bf16 bf16x8;
typedef __attribute__((ext_vector_type(4))) float f32x4;
typedef __attribute__((ext_vector_type(8))) unsigned short u16x8;

__device__ __forceinline__ unsigned short f2b(float f) {
  union { float f; unsigned u; } v; v.f = f;
  unsigned r = v.u + 0x7FFFu + ((v.u >> 16) & 1u);
  return (unsigned short)(r >> 16);
}
__device__ __forceinline__ float b2f(unsigned short b) {
  union { unsigned u; float f; } v; v.u = ((unsigned)b) << 16;
  return v.f;
}

__device__ __forceinline__ void f2b_body(const float* __restrict__ src,
                                         unsigned short* __restrict__ dst,
                                         int n8, int b, int nb) {
  int i = b * 256 + (threadIdx.x & 255);
  const int stride = nb * 256;
  for (; i < n8; i += stride) {
    const float4* s4 = ((const float4*)src) + (long)i * 2;
    float4 a = s4[0], c = s4[1];
    u16x8 o;
    o[0] = f2b(a.x); o[1] = f2b(a.y); o[2] = f2b(a.z); o[3] = f2b(a.w);
    o[4] = f2b(c.x); o[5] = f2b(c.y); o[6] = f2b(c.z); o[7] = f2b(c.w);
    ((u16x8*)dst)[i] = o;
  }
}

__device__ __forceinline__ void f2b_body512(const float* __restrict__ src,
                                            unsigned short* __restrict__ dst,
                                            int n8, int b, int nb) {
  int i = b * 512 + (int)threadIdx.x;
  const int stride = nb * 512;
  for (; i < n8; i += stride) {
    const float4* s4 = ((const float4*)src) + (long)i * 2;
    float4 a = s4[0], c = s4[1];
    u16x8 o;
    o[0] = f2b(a.x); o[1] = f2b(a.y); o[2] = f2b(a.z); o[3] = f2b(a.w);
    o[4] = f2b(c.x); o[5] = f2b(c.y); o[6] = f2b(c.z); o[7] = f2b(c.w);
    ((u16x8*)dst)[i] = o;
  }
}

// -------- gating (fp32-exact) + fused f2b(W1) in trailing blocks -----------
__global__ __launch_bounds__(256) void gate_kernel(
    const float* __restrict__ x, const float* __restrict__ Wg,
    int* __restrict__ idx, float* __restrict__ pw,
    const float* __restrict__ fsrc, unsigned short* __restrict__ fdst,
    int n8, int ngate)
{
  if ((int)blockIdx.x >= ngate) {
    f2b_body(fsrc, fdst, n8, blockIdx.x - ngate, gridDim.x - ngate);
    return;
  }
  const int wave = threadIdx.x >> 6, lane = threadIdx.x & 63;
  const int token = blockIdx.x * 4 + wave;
  const float4* xr = (const float4*)(x + (long)token * DIM);
  float4 xv[4];
#pragma unroll
  for (int p = 0; p < 4; ++p) xv[p] = xr[p * 64 + lane];
  float s[8];
#pragma unroll
  for (int e = 0; e < 8; ++e) {
    const float4* wr = (const float4*)(Wg + e * DIM);
    float acc = 0.f;
#pragma unroll
    for (int p = 0; p < 4; ++p) {
      float4 wv = wr[p * 64 + lane];
      acc += xv[p].x * wv.x + xv[p].y * wv.y + xv[p].z * wv.z + xv[p].w * wv.w;
    }
    s[e] = acc;
  }
#pragma unroll
  for (int o = 32; o; o >>= 1)
#pragma unroll
    for (int e = 0; e < 8; ++e) s[e] += __shfl_xor(s[e], o, 64);

  if (lane == 0) {
    int e1 = 0; float s1 = s[0];
#pragma unroll
    for (int e = 1; e < 8; ++e) if (s[e] > s1) { s1 = s[e]; e1 = e; }
    int e2 = -1; float s2 = -1e30f;
#pragma unroll
    for (int e = 0; e < 8; ++e) { if (e == e1) continue; if (s[e] > s2) { s2 = s[e]; e2 = e; } }
    float t = expf(s2 - s1);
    float p1 = 1.f / (1.f + t);
    float p2 = t * p1;
    idx[2 * token] = e1; idx[2 * token + 1] = e2;
    pw[2 * token] = p1;  pw[2 * token + 1] = p2;
  }
}

// ------- ordered capacity scan: 16 waves, wave-local scan + prefix ---------
__global__ __launch_bounds__(1024) void scan_kernel(
    const int* __restrict__ idx, const float* __restrict__ pw,
    int* __restrict__ pos_out, float* __restrict__ w_out,
    float* __restrict__ aux_out)
{
  __shared__ int wcnt[SCAN_WAVES * 8];
  __shared__ int woff[SCAN_WAVES * 8];
  __shared__ float redc[SCAN_WAVES * 8];
  __shared__ float redi[SCAN_WAVES * 8];
  const int t = threadIdx.x, w = t >> 6, lane = t & 63;
  const unsigned long long below = (1ull << lane) - 1ull;
  const int base_s = w * (NSLOT / SCAN_WAVES);

  int e_r[16]; float p_r[16]; int lp_r[16];
  int base[8] = {0, 0, 0, 0, 0, 0, 0, 0};
  for (int r = 0; r < 16; ++r) {
    const int s = base_s + r * 64 + lane;
    const int e = idx[s];
    const float p = pw[s];
    e_r[r] = e; p_r[r] = p;
    int mypos = 0;
#pragma unroll
    for (int q = 0; q < 8; ++q) {
      unsigned long long m = __ballot(e == q);
      if (e == q) mypos = base[q] + __popcll(m & below);
      base[q] += __popcll(m);
    }
    lp_r[r] = mypos;
  }
  if (lane < 8) wcnt[w * 8 + lane] = base[lane];
  __syncthreads();
  if (t < SCAN_WAVES * 8) {
    const int ww = t >> 3, q = t & 7;
    int acc = 0;
    for (int w2 = 0; w2 < ww; ++w2) acc += wcnt[w2 * 8 + q];
    woff[t] = acc;
  }
  __syncthreads();
  int off8[8];
#pragma unroll
  for (int q = 0; q < 8; ++q) off8[q] = woff[w * 8 + q];

  float cnt[8] = {0, 0, 0, 0, 0, 0, 0, 0};
  float imp[8] = {0, 0, 0, 0, 0, 0, 0, 0};
  for (int r = 0; r < 16; ++r) {
    const int s = base_s + r * 64 + lane;
    const int e = e_r[r];
    const int gpos = off8[e] + lp_r[r];
    const bool keep = gpos < CAP;
    const float wk = keep ? p_r[r] : 0.f;
    const float wp = __shfl_xor(wk, 1, 64);
    const float wn = wk / (wk + wp + 1e-9f);
    const bool valid = wn > 0.f;
    pos_out[s] = valid ? gpos : -1;
    w_out[s] = wn;
    if (valid) { cnt[e] += 1.f; imp[e] += wn; }
  }
#pragma unroll
  for (int q = 0; q < 8; ++q)
#pragma unroll
    for (int o = 32; o; o >>= 1) {
      cnt[q] += __shfl_xor(cnt[q], o, 64);
      imp[q] += __shfl_xor(imp[q], o, 64);
    }
  if (lane < 8) { redc[w * 8 + lane] = cnt[lane]; redi[w * 8 + lane] = imp[lane]; }
  __syncthreads();
  if (t == 0) {
    float c8[8] = {0, 0, 0, 0, 0, 0, 0, 0};
    float i8[8] = {0, 0, 0, 0, 0, 0, 0, 0};
    float T = 0.f, I = 0.f;
    for (int w2 = 0; w2 < SCAN_WAVES; ++w2)
      for (int q = 0; q < 8; ++q) { c8[q] += redc[w2 * 8 + q]; i8[q] += redi[w2 * 8 + q]; }
    for (int q = 0; q < 8; ++q) { T += c8[q]; I += i8[q]; }
    float aux = 0.f;
    for (int q = 0; q < 8; ++q) aux += (c8[q] / T) * (i8[q] / I);
    aux_out[0] = aux * 8.f;
  }
}

// ---------------- dispatch: X[e][pos] = x[token] * w (bf16) ----------------
__global__ __launch_bounds__(128) void dispatch_kernel(
    const float* __restrict__ x, const int* __restrict__ idx,
    const int* __restrict__ pos, const float* __restrict__ w,
    unsigned short* __restrict__ X)
{
  const int s = blockIdx.x;
  const int p = pos[s];
  if (p < 0) return;
  const int e = idx[s];
  const float wt = w[s];
  const int t = threadIdx.x;
  const float4* xr = (const float4*)(x + ((long)(s >> 1)) * DIM);
  float4 a = xr[t * 2], b = xr[t * 2 + 1];
  u16x8 o;
  o[0] = f2b(a.x * wt); o[1] = f2b(a.y * wt); o[2] = f2b(a.z * wt); o[3] = f2b(a.w * wt);
  o[4] = f2b(b.x * wt); o[5] = f2b(b.y * wt); o[6] = f2b(b.z * wt); o[7] = f2b(b.w * wt);
  *(u16x8*)(X + ((long)e * CAP + p) * DIM + t * 8) = o;
}

// ---------------- standalone fp32 -> bf16 (fallback path) ------------------
__global__ __launch_bounds__(256) void f2b_kernel(
    const float* __restrict__ src, unsigned short* __restrict__ dst, int n8)
{
  f2b_body(src, dst, n8, blockIdx.x, gridDim.x);
}

// ===========================================================================
// 256x256 8-phase GEMM (T1+T2+T3+T4+T5): C[e] = A[e](MxK) * B[e]^T(NxK), bf16
//   512 thr = 8 waves (2M x 4N), wave tile 128x64, BK=64, LDS 128 KiB 2-dbuf.
//   A LDS region-remapped: region0={rows 0-63,128-191}, region1={64-127,192-255}
//   so every staged half-tile overwrites only regions dead >=1 barrier-pair ago.
//   XOR swizzle: elem_off ^= ((row&7)<<3)  (byte ^= (row&7)<<4), applied on the
//   pre-swizzled GLOBAL source (gload_lds writes linearly) + on ds_read addr.
//   vmcnt ledger: 2 loads/half-tile; vmcnt(6) at phases 4,8 completes exactly
//   the 4 oldest of 7 in-flight half-tiles = the buffer consumed next.
//   Tail iterations drop to vmcnt(0) (fewer issues -> constant 6 releases early).
//   Requires K % 128 == 0, M % 256 == 0, N % 256 == 0.
// ===========================================================================
__global__ __launch_bounds__(512, 2) void gemm8p(
    const unsigned short* __restrict__ A, const unsigned short* __restrict__ B,
    unsigned short* __restrict__ C, int M, int N, int K, int relu,
    int Mt, int Nt, int nGemm,
    const float* __restrict__ fsrc, unsigned short* __restrict__ fdst, int n8)
{
  __shared__ unsigned short sA[2][2][8192];   // [dbuf][region][128*64]
  __shared__ unsigned short sB[2][2][8192];   // [dbuf][half  ][128*64]
  const int bid = blockIdx.x;
  if (bid >= nGemm) {
    f2b_body512(fsrc, fdst, n8, bid - nGemm, gridDim.x - nGemm);
    return;
  }
  // XCD-pinned bijective swizzle (nGemm % 8 == 0): expert e -> XCD e.
  const int per = nGemm >> 3;                 // = Mt*Nt
  const int swzb = (bid & 7) * per + (bid >> 3);
  const int e = swzb / per, slot = swzb % per;
  const int m0 = (slot % Mt) * 256, n0 = (slot / Mt) * 256;
  (void)Nt;

  const unsigned short* Ae = A + (long)e * M * K + (long)m0 * K;
  const unsigned short* Be = B + (long)e * N * K + (long)n0 * K;
  unsigned short* Ce = C + (long)e * M * N;

  const int t = threadIdx.x, w = t >> 6, lane = t & 63;
  const int fr = lane & 15, qw = lane >> 4;
  const int wm = (w >> 2) * 128, wn = (w & 3) * 64;

  // staging: thread t covers LDS linear elems [l*4096 + t*8, +8); row = l*64+(t>>3)
  const int tR0 = t >> 3;
  const int ssw = ((t & 7) * 8) ^ ((tR0 & 7) << 3);      // pre-swizzled src offset
  // read: elem off within row = (ks*32 + qw*8) ^ ((fr&7)<<3)
  const int base0 = (qw * 8) ^ ((fr & 7) << 3);
  const int base1 = base0 ^ 32;
  const int rowA = ((w >> 2) * 64 + fr) * 64;            // region-local row * 64
  const int rowB = ((w & 1) * 64 + fr) * 64;
  const int hB = (w & 3) >> 1;

  auto stageA = [&](int d, int r, int kb) {
#pragma unroll
    for (int l = 0; l < 2; ++l)
      __builtin_amdgcn_global_load_lds(
          (const __attribute__((address_space(1))) void*)
              (Ae + (long)(tR0 + l * 128 + r * 64) * K + kb + ssw),
          (__attribute__((address_space(3))) void*)
              (&sA[d][r][0] + l * 4096 + w * 512), 16, 0, 0);
  };
  auto stageB = [&](int d, int h, int kb) {
#pragma unroll
    for (int l = 0; l < 2; ++l)
      __builtin_amdgcn_global_load_lds(
          (const __attribute__((address_space(1))) void*)
              (Be + (long)(tR0 + l * 64 + h * 128) * K + kb + ssw),
          (__attribute__((address_space(3))) void*)
              (&sB[d][h][0] + l * 4096 + w * 512), 16, 0, 0);
  };

  bf16x8 a[4][2], b0[2][2], b1[2][2];
  f32x4 acc[8][4] = {};

  auto ldA = [&](int d, int g) {
    const unsigned short* p = &sA[d][g][0] + rowA;
#pragma unroll
    for (int i = 0; i < 4; ++i) {
      a[i][0] = *(const bf16x8*)(p + i * 1024 + base0);
      a[i][1] = *(const bf16x8*)(p + i * 1024 + base1);
    }
  };
  auto ldB = [&](int d, int njG, bf16x8 (&bb)[2][2]) {
    const unsigned short* p = &sB[d][hB][0] + rowB + njG * 2048;
#pragma unroll
    for (int j = 0; j < 2; ++j) {
      bb[j][0] = *(const bf16x8*)(p + j * 1024 + base0);
      bb[j][1] = *(const bf16x8*)(p + j * 1024 + base1);
    }
  };
  auto mm = [&](int miG, int njG, bf16x8 (&bb)[2][2]) {
    __builtin_amdgcn_s_setprio(1);
#pragma unroll
    for (int i = 0; i < 4; ++i)
#pragma unroll
      for (int j = 0; j < 2; ++j)
#pragma unroll
        for (int ks = 0; ks < 2; ++ks)
          acc[miG * 4 + i][njG * 2 + j] = __builtin_amdgcn_mfma_f32_16x16x32_bf16(
              a[i][ks], bb[j][ks], acc[miG * 4 + i][njG * 2 + j], 0, 0, 0);
    __builtin_amdgcn_s_setprio(0);
  };

  // prologue: K-tile0 full (4 half-tiles) + K-tile1 {Ar0,B0,B1}
  stageA(0, 0, 0); stageA(0, 1, 0); stageB(0, 0, 0); stageB(0, 1, 0);
  stageA(1, 0, 64); stageB(1, 0, 64); stageB(1, 1, 64);
  asm volatile("s_waitcnt vmcnt(6)" ::: "memory");   // completes K-tile0 (8 oldest)
  __builtin_amdgcn_s_barrier();

  const int nkt = K >> 6;
#pragma unroll 1
  for (int it = 0; it < (nkt >> 1); ++it) {
    const int kb1 = (2 * it + 1) << 6;
    const int kt2 = 2 * it + 2, kt3 = 2 * it + 3;
    const int kb2 = kt2 << 6, kb3 = kt3 << 6;
    const bool s2 = kt2 < nkt, s3 = kt3 < nkt;
    // ---- p1: reads d0.Ar0 + d0.B(nj01); stage d1.Ar1 <- tile 2it+1
    ldA(0, 0); ldB(0, 0, b0);
    stageA(1, 1, kb1);
    __builtin_amdgcn_s_barrier();
    asm volatile("s_waitcnt lgkmcnt(0)" ::: "memory");
    mm(0, 0, b0);
    __builtin_amdgcn_s_barrier();
    // ---- p2: reads d0.B(nj23); stage d0.Ar0 <- tile 2it+2 (Ar0 dead since p1)
    ldB(0, 1, b1);
    if (s2) stageA(0, 0, kb2);
    __builtin_amdgcn_s_barrier();
    asm volatile("s_waitcnt lgkmcnt(0)" ::: "memory");
    mm(0, 1, b1);
    __builtin_amdgcn_s_barrier();
    // ---- p3: reads d0.Ar1; stage d0.B0 (all B dead since p2)
    ldA(0, 1);
    if (s2) stageB(0, 0, kb2);
    __builtin_amdgcn_s_barrier();
    asm volatile("s_waitcnt lgkmcnt(0)" ::: "memory");
    mm(1, 1, b1);
    __builtin_amdgcn_s_barrier();
    // ---- p4: no reads; stage d0.B1; FENCE -> d1 (tile 2it+1) fully resident
    if (s2) stageB(0, 1, kb2);
    if (s2) asm volatile("s_waitcnt vmcnt(6)" ::: "memory");
    else    asm volatile("s_waitcnt vmcnt(0)" ::: "memory");
    __builtin_amdgcn_s_barrier();
    mm(1, 0, b0);
    __builtin_amdgcn_s_barrier();
    // ---- p5: reads d1.Ar0 + d1.B(nj01); stage d0.Ar1 (dead since p3)
    ldA(1, 0); ldB(1, 0, b0);
    if (s2) stageA(0, 1, kb2);
    __builtin_amdgcn_s_barrier();
    asm volatile("s_waitcnt lgkmcnt(0)" ::: "memory");
    mm(0, 0, b0);
    __builtin_amdgcn_s_barrier();
    // ---- p6: reads d1.B(nj23); stage d1.Ar0 <- tile 2it+3
    ldB(1, 1, b1);
    if (s3) stageA(1, 0, kb3);
    __builtin_amdgcn_s_barrier();
    asm volatile("s_waitcnt lgkmcnt(0)" ::: "memory");
    mm(0, 1, b1);
    __builtin_amdgcn_s_barrier();
    // ---- p7: reads d1.Ar1; stage d1.B0
    ldA(1, 1);
    if (s3) stageB(1, 0, kb3);
    __builtin_amdgcn_s_barrier();
    asm volatile("s_waitcnt lgkmcnt(0)" ::: "memory");
    mm(1, 1, b1);
    __builtin_amdgcn_s_barrier();
    // ---- p8: no reads; stage d1.B1; FENCE -> d0 (tile 2it+2) fully resident
    if (s3) stageB(1, 1, kb3);
    if (s3) asm volatile("s_waitcnt vmcnt(6)" ::: "memory");
    else    asm volatile("s_waitcnt vmcnt(0)" ::: "memory");
    __builtin_amdgcn_s_barrier();
    mm(1, 0, b0);
    __builtin_amdgcn_s_barrier();
  }

  // epilogue: C/D layout col=lane&15, row=(lane>>4)*4+reg  [m89/m91 verified]
  const int rr = (lane >> 4) * 4, cc = lane & 15;
#pragma unroll
  for (int mi = 0; mi < 8; ++mi)
#pragma unroll
    for (int nj = 0; nj < 4; ++nj)
#pragma unroll
      for (int r = 0; r < 4; ++r) {
        float v = acc[mi][nj][r];
        if (relu) v = fmaxf(v, 0.f);
        Ce[(long)(m0 + wm + mi * 16 + rr + r) * N + (n0 + wn + nj * 16 + cc)] = f2b(v);
      }
}

// ---------------- combine: y[token] = sum of its valid slot rows -----------
__global__ __launch_bounds__(128) void combine_kernel(
    const unsigned short* __restrict__ Y, const int* __restrict__ idx,
    const int* __restrict__ pos, float* __restrict__ y)
{
  const int n = blockIdx.x, t = threadIdx.x;
  const int p0 = pos[2 * n], p1 = pos[2 * n + 1];
  float a[8] = {0.f, 0.f, 0.f, 0.f, 0.f, 0.f, 0.f, 0.f};
  if (p0 >= 0) {
    const int e = idx[2 * n];
    u16x8 v = *(const u16x8*)(Y + ((long)e * CAP + p0) * DIM + t * 8);
#pragma unroll
    for (int r = 0; r < 8; ++r) a[r] += b2f(v[r]);
  }
  if (p1 >= 0) {
    const int e = idx[2 * n + 1];
    u16x8 v = *(const u16x8*)(Y + ((long)e * CAP + p1) * DIM + t * 8);
#pragma unroll
    for (int r = 0; r < 8; ++r) a[r] += b2f(v[r]);
  }
  float4* out = (float4*)(y + (long)n * DIM + t * 8);
  out[0] = make_float4(a[0], a[1], a[2], a[3]);
  out[1] = make_float4(a[4], a[5], a[6], a[7]);
}

extern "C" void kernel_launch(void* const* d_in, const int* in_sizes, int n_in,
                              void* d_out, int out_size, void* d_ws, size_t ws_size,
                              hipStream_t stream)
{
  const float* x  = (const float*)d_in[0];
  const float* Wg = (const float*)d_in[1];
  const float* W1 = (const float*)d_in[2];
  const float* W2 = (const float*)d_in[3];
  float* y   = (float*)d_out;
  float* aux = y + (long)N_TOK * DIM;

  char* ws = (char*)d_ws;
  size_t off = 0;
  auto alloc = [&](size_t bytes) -> void* {
    void* p = ws + off;
    off = (off + bytes + 255) & ~(size_t)255;
    return p;
  };
  int*            idx  = (int*)alloc(NSLOT * 4);
  float*          pw   = (float*)alloc(NSLOT * 4);
  int*            pos  = (int*)alloc(NSLOT * 4);
  float*          w    = (float*)alloc(NSLOT * 4);
  unsigned short* Xbf  = (unsigned short*)alloc((size_t)NEXP * CAP * DIM * 2);
  unsigned short* Hbf  = (unsigned short*)alloc((size_t)NEXP * CAP * DFF * 2);
  unsigned short* Ybf  = (unsigned short*)alloc((size_t)NEXP * CAP * DIM * 2);
  unsigned short* Wbf1 = (unsigned short*)alloc((size_t)NEXP * DFF * DIM * 2);
  unsigned short* Wbf2 = (unsigned short*)alloc((size_t)NEXP * DFF * DIM * 2);
  const bool big = ws_size >= off;          // ws_size constant across calls

  const int n8w = NEXP * DFF * DIM / 8;

  // gate (2048 blocks) + fused f2b(W1) (512 blocks)
  gate_kernel<<<2048 + 512, 256, 0, stream>>>(x, Wg, idx, pw, W1, Wbf1, n8w, 2048);
  scan_kernel<<<1, 1024, 0, stream>>>(idx, pw, pos, w, aux);
  dispatch_kernel<<<NSLOT, 128, 0, stream>>>(x, idx, pos, w, Xbf);

  if (big) {
    // GEMM1: 640 gemm blocks (8e x 5m x 16n) + 128 trailing f2b(W2) blocks
    // (grid 768 = 3 full rounds of 256 CUs; f2b fills the round-3 tail)
    gemm8p<<<640 + 128, 512, 0, stream>>>(Xbf, Wbf1, Hbf, CAP, DFF, DIM, 1,
                                          5, 16, 640, W2, Wbf2, n8w);
    gemm8p<<<160, 512, 0, stream>>>(Hbf, Wbf2, Ybf, CAP, DIM, DFF, 0,
                                    5, 4, 160, nullptr, nullptr, 0);
  } else {
    gemm8p<<<640, 512, 0, stream>>>(Xbf, Wbf1, Hbf, CAP, DFF, DIM, 1,
                                    5, 16, 640, nullptr, nullptr, 0);
    f2b_kernel<<<512, 256, 0, stream>>>(W2, Wbf1, n8w);
    gemm8p<<<160, 512, 0, stream>>>(Hbf, Wbf1, Ybf, CAP, DIM, DFF, 0,
                                    5, 4, 160, nullptr, nullptr, 0);
  }
  combine_kernel<<<N_TOK, 128, 0, stream>>>(Ybf, idx, pos, y);
}